// Round 1
// baseline (195.719 us; speedup 1.0000x reference)
//
#include <hip/hip_runtime.h>

// QKBmm: out[b,m,q,kv] = sum_h q[b,m,q,h] * k[b,m,kv,h]
// B=2, M=16, QT=1024, KVT=4096, H=128. fp32 in/out, bf16 MFMA compute.

#define QT   1024
#define KVT  4096
#define HD   128
#define NBM  32     // B*M batched GEMMs

using bf16x8 = __attribute__((ext_vector_type(8))) __bf16;
using bf16x4 = __attribute__((ext_vector_type(4))) __bf16;
using f32x4  = __attribute__((ext_vector_type(4))) float;

__global__ __launch_bounds__(256, 2)
void QKBmm_74062416052397_kernel(const float* __restrict__ q,
                                 const float* __restrict__ k,
                                 float* __restrict__ out) {
    // 128x128 bf16 tiles, XOR-swizzled to kill the stride-256B bank conflict
    __shared__ __bf16 As[128 * 128];
    __shared__ __bf16 Bs[128 * 128];

    const int t  = threadIdx.x;        // 0..255
    const int bm = blockIdx.z;         // batch*M index
    const int m0 = blockIdx.y * 128;   // Q-row tile base
    const int n0 = blockIdx.x * 128;   // KV-col tile base

    // Tiles cover the full head dim -> contiguous 64KB chunks in global.
    const float* __restrict__ Qp = q + ((size_t)bm * QT  + m0) * HD;
    const float* __restrict__ Kp = k + ((size_t)bm * KVT + n0) * HD;

    // ---- Stage: fp32 -> bf16 into LDS (coalesced float4 loads) ----
#pragma unroll
    for (int i = 0; i < 16; ++i) {
        int f   = i * 256 + t;        // float4 index within tile [0,4096)
        int row = f >> 5;             // 32 float4 per 128-wide row
        float4 va = reinterpret_cast<const float4*>(Qp)[f];
        float4 vb = reinterpret_cast<const float4*>(Kp)[f];
        bf16x4 pa = { (__bf16)va.x, (__bf16)va.y, (__bf16)va.z, (__bf16)va.w };
        bf16x4 pb = { (__bf16)vb.x, (__bf16)vb.y, (__bf16)vb.z, (__bf16)vb.w };
        int e = (f << 2) ^ ((row & 7) << 3);   // element index, swizzled
        *reinterpret_cast<bf16x4*>(&As[e]) = pa;
        *reinterpret_cast<bf16x4*>(&Bs[e]) = pb;
    }
    __syncthreads();

    // ---- MFMA: each wave computes a 64x64 sub-tile ----
    const int lane = t & 63;
    const int wid  = t >> 6;
    const int wm   = (wid >> 1) * 64;  // wave row offset within tile
    const int wn   = (wid & 1) * 64;   // wave col offset within tile
    const int lr   = lane & 15;        // fragment row/col index
    const int lg   = lane >> 4;        // k-group 0..3

    f32x4 acc[4][4] = {};

#pragma unroll
    for (int ks = 0; ks < 4; ++ks) {
        const int kcol = ks * 32 + lg * 8;
        bf16x8 af[4], bfr[4];
#pragma unroll
        for (int mi = 0; mi < 4; ++mi) {
            int r = wm + mi * 16 + lr;
            int e = (r * 128 + kcol) ^ ((r & 7) << 3);
            af[mi] = *reinterpret_cast<const bf16x8*>(&As[e]);
        }
#pragma unroll
        for (int ni = 0; ni < 4; ++ni) {
            int r = wn + ni * 16 + lr;
            int e = (r * 128 + kcol) ^ ((r & 7) << 3);
            bfr[ni] = *reinterpret_cast<const bf16x8*>(&Bs[e]);
        }
#pragma unroll
        for (int mi = 0; mi < 4; ++mi)
#pragma unroll
            for (int ni = 0; ni < 4; ++ni)
                acc[mi][ni] = __builtin_amdgcn_mfma_f32_16x16x32_bf16(
                    af[mi], bfr[ni], acc[mi][ni], 0, 0, 0);
    }

    // ---- Epilogue: C/D layout col=lane&15, row=(lane>>4)*4+reg ----
    float* __restrict__ Cp = out + (size_t)bm * QT * KVT;
#pragma unroll
    for (int mi = 0; mi < 4; ++mi) {
#pragma unroll
        for (int j = 0; j < 4; ++j) {
            int row = m0 + wm + mi * 16 + lg * 4 + j;
            float* rp = Cp + (size_t)row * KVT + n0 + wn;
#pragma unroll
            for (int ni = 0; ni < 4; ++ni)
                rp[ni * 16 + lr] = acc[mi][ni][j];
        }
    }
}

extern "C" void kernel_launch(void* const* d_in, const int* in_sizes, int n_in,
                              void* d_out, int out_size, void* d_ws, size_t ws_size,
                              hipStream_t stream) {
    const float* q = (const float*)d_in[0];
    const float* k = (const float*)d_in[1];
    float* out = (float*)d_out;

    dim3 grid(KVT / 128, QT / 128, NBM);   // (32, 8, 32)
    QKBmm_74062416052397_kernel<<<grid, dim3(256), 0, stream>>>(q, k, out);
}

// Round 2
// 136.312 us; speedup vs baseline: 1.4358x; 1.4358x over previous
//
#include <hip/hip_runtime.h>

// QKBmm: out[b,m,q,kv] = sum_h q[b,m,q,h] * k[b,m,kv,h]
// B=2, M=16, QT=1024, KVT=4096, H=128. fp32 in/out, bf16 MFMA compute.
// Write-bound: 512 MB out + ~84 MB compulsory reads -> ~96us floor.
// R2: nontemporal output stores (protect L2/L3 from the write stream) +
//     XCD-aware swizzle (q/k tiles served from XCD-local L2).

#define QT   1024
#define KVT  4096
#define HD   128
#define NBM  32     // B*M batched GEMMs
#define NXCD 8

using bf16x8 = __attribute__((ext_vector_type(8))) __bf16;
using bf16x4 = __attribute__((ext_vector_type(4))) __bf16;
using f32x4  = __attribute__((ext_vector_type(4))) float;

__global__ __launch_bounds__(256, 2)
void QKBmm_74062416052397_kernel(const float* __restrict__ q,
                                 const float* __restrict__ k,
                                 float* __restrict__ out) {
    // 128x128 bf16 tiles, XOR-swizzled to kill the stride-256B bank conflict
    __shared__ __bf16 As[128 * 128];
    __shared__ __bf16 Bs[128 * 128];

    const int t = threadIdx.x;         // 0..255

    // XCD-aware remap: 8192 blocks, 1024 contiguous per XCD (bijective: 8192%8==0).
    // Within a chunk: n fastest (q-tile reuse x32), then m (k-slice reuse x8, 2MB < 4MB L2).
    const unsigned lin = blockIdx.x;
    const unsigned swz = (lin & (NXCD - 1)) * (8192u / NXCD) + (lin >> 3);
    const int nt_ = swz & 31;          // KV tile index (fastest)
    const int mt  = (swz >> 5) & 7;    // Q tile index
    const int bm  = swz >> 8;          // batch*M index
    const int m0  = mt * 128;
    const int n0  = nt_ * 128;

    // Tiles cover the full head dim -> contiguous 64KB chunks in global.
    const float* __restrict__ Qp = q + ((size_t)bm * QT  + m0) * HD;
    const float* __restrict__ Kp = k + ((size_t)bm * KVT + n0) * HD;

    // ---- Stage: fp32 -> bf16 into LDS (coalesced float4 loads) ----
#pragma unroll
    for (int i = 0; i < 16; ++i) {
        int f   = i * 256 + t;        // float4 index within tile [0,4096)
        int row = f >> 5;             // 32 float4 per 128-wide row
        float4 va = reinterpret_cast<const float4*>(Qp)[f];
        float4 vb = reinterpret_cast<const float4*>(Kp)[f];
        bf16x4 pa = { (__bf16)va.x, (__bf16)va.y, (__bf16)va.z, (__bf16)va.w };
        bf16x4 pb = { (__bf16)vb.x, (__bf16)vb.y, (__bf16)vb.z, (__bf16)vb.w };
        int e = (f << 2) ^ ((row & 7) << 3);   // element index, swizzled
        *reinterpret_cast<bf16x4*>(&As[e]) = pa;
        *reinterpret_cast<bf16x4*>(&Bs[e]) = pb;
    }
    __syncthreads();

    // ---- MFMA: each wave computes a 64x64 sub-tile ----
    const int lane = t & 63;
    const int wid  = t >> 6;
    const int wm   = (wid >> 1) * 64;  // wave row offset within tile
    const int wn   = (wid & 1) * 64;   // wave col offset within tile
    const int lr   = lane & 15;        // fragment row/col index
    const int lg   = lane >> 4;        // k-group 0..3

    f32x4 acc[4][4] = {};

#pragma unroll
    for (int ks = 0; ks < 4; ++ks) {
        const int kcol = ks * 32 + lg * 8;
        bf16x8 af[4], bfr[4];
#pragma unroll
        for (int mi = 0; mi < 4; ++mi) {
            int r = wm + mi * 16 + lr;
            int e = (r * 128 + kcol) ^ ((r & 7) << 3);
            af[mi] = *reinterpret_cast<const bf16x8*>(&As[e]);
        }
#pragma unroll
        for (int ni = 0; ni < 4; ++ni) {
            int r = wn + ni * 16 + lr;
            int e = (r * 128 + kcol) ^ ((r & 7) << 3);
            bfr[ni] = *reinterpret_cast<const bf16x8*>(&Bs[e]);
        }
#pragma unroll
        for (int mi = 0; mi < 4; ++mi)
#pragma unroll
            for (int ni = 0; ni < 4; ++ni)
                acc[mi][ni] = __builtin_amdgcn_mfma_f32_16x16x32_bf16(
                    af[mi], bfr[ni], acc[mi][ni], 0, 0, 0);
    }

    // ---- Epilogue: C/D layout col=lane&15, row=(lane>>4)*4+reg ----
    // Nontemporal: the 512MB output is never re-read; don't thrash L2/L3.
    float* __restrict__ Cp = out + (size_t)bm * QT * KVT;
#pragma unroll
    for (int mi = 0; mi < 4; ++mi) {
#pragma unroll
        for (int j = 0; j < 4; ++j) {
            int row = m0 + wm + mi * 16 + lg * 4 + j;
            float* rp = Cp + (size_t)row * KVT + n0 + wn;
#pragma unroll
            for (int ni = 0; ni < 4; ++ni)
                __builtin_nontemporal_store(acc[mi][ni][j], rp + ni * 16 + lr);
        }
    }
}

extern "C" void kernel_launch(void* const* d_in, const int* in_sizes, int n_in,
                              void* d_out, int out_size, void* d_ws, size_t ws_size,
                              hipStream_t stream) {
    const float* q = (const float*)d_in[0];
    const float* k = (const float*)d_in[1];
    float* out = (float*)d_out;

    QKBmm_74062416052397_kernel<<<dim3(8192), dim3(256), 0, stream>>>(q, k, out);
}